// Round 5
// baseline (277.184 us; speedup 1.0000x reference)
//
#include <hip/hip_runtime.h>
#include <hip/hip_bf16.h>

// CCAM (fp32 in/out, confirmed round 2): x (16,1024,64,64), martx (4096,64).
// rows = B*C = 16384, N = 4096 spatial, KDIM = 64.
// energy[r][k] = sum_n x[r][n] * M[n][k]           (GEMM1, K=4096)
// att = softmax(alpha * (rowmax(energy) - energy))  (64-wide)
// out[r][n] = gamma * sum_k att[r][k]*M[n][k] + x[r][n]
//
// Round-5: same validated dataflow as round 4; schedule rebuilt for occupancy
// and memory-level parallelism:
//   - 512 threads (8 waves), 4 blocks/CU -> 32 waves/CU (exactly full chip)
//   - phase 1: raw s_barrier + counted vmcnt (DMAs stay in flight across
//     barriers; no vmcnt(0) drains in the loop)  [T3/T4]
//   - phase 3: wave-private, no barriers, residual DMA pipelined 1 grp ahead

using frag_ab = __attribute__((ext_vector_type(8))) short;   // 8 bf16 = 4 VGPR
using f32x4   = __attribute__((ext_vector_type(4))) float;   // MFMA C/D

#define MFMA16(a, b, c) __builtin_amdgcn_mfma_f32_16x16x32_bf16((a), (b), (c), 0, 0, 0)
#define AS1(p) ((const __attribute__((address_space(1))) void*)(p))
#define AS3(p) ((__attribute__((address_space(3))) void*)(p))
#define SBAR() __builtin_amdgcn_sched_barrier(0)

static __device__ __forceinline__ unsigned short f2bf_bits(float f) {
    __hip_bfloat16 h = __float2bfloat16(f);
    return *reinterpret_cast<const unsigned short*>(&h);
}
static __device__ __forceinline__ frag_ab load_frag(const __hip_bfloat16* p) {
    return *reinterpret_cast<const frag_ab*>(p);
}
static __device__ __forceinline__ frag_ab cvt2(float4 a, float4 b) {
    frag_ab r;
    r[0] = (short)f2bf_bits(a.x); r[1] = (short)f2bf_bits(a.y);
    r[2] = (short)f2bf_bits(a.z); r[3] = (short)f2bf_bits(a.w);
    r[4] = (short)f2bf_bits(b.x); r[5] = (short)f2bf_bits(b.y);
    r[6] = (short)f2bf_bits(b.z); r[7] = (short)f2bf_bits(b.w);
    return r;
}

// -------- kernel 0: build frag-linear B banks (unchanged, validated) --------
// MtF  (512 frags x 1 KB): frag f = slot*4+t, elem (lane,j) = M[32*slot+8g+j][16t+r15]
// MbfF (512 frags x 1 KB): frag f = nt*2+h,   elem (lane,j) = M[16nt+r15][32h+8g+j]
__global__ __launch_bounds__(256) void prep_frags(
        const float* __restrict__ M,
        __hip_bfloat16* __restrict__ MtF, __hip_bfloat16* __restrict__ MbfF) {
    const int w    = threadIdx.x >> 6;
    const int lane = threadIdx.x & 63;
    const int g    = lane >> 4;
    const int r15  = lane & 15;
    const int f    = blockIdx.x * 4 + w;    // 0..1023
    if (f < 512) {
        const int slot = f >> 2, t = f & 3;
        frag_ab fr;
#pragma unroll
        for (int j = 0; j < 8; ++j)
            fr[j] = (short)f2bf_bits(M[(size_t)(32 * slot + 8 * g + j) * 64 + 16 * t + r15]);
        *reinterpret_cast<frag_ab*>(MtF + ((size_t)f * 64 + lane) * 8) = fr;
    } else {
        const int f2 = f - 512;
        const float* src = M + (size_t)(16 * (f2 >> 1) + r15) * 64 + 32 * (f2 & 1) + 8 * g;
        float4 a = *reinterpret_cast<const float4*>(src);
        float4 b = *reinterpret_cast<const float4*>(src + 4);
        *reinterpret_cast<frag_ab*>(MbfF + ((size_t)f2 * 64 + lane) * 8) = cvt2(a, b);
    }
}

// -------- kernel 1: fused CCAM ----------------------------------------------
// LDS (34816 B):
//   xbuf0 [0,16640)   : 16 rows x 260 floats (1040 B stride)
//   xbuf1 [16640,33280)
//   Ep[8][16][68]     : overlay [0,34816)  (live: after phase-1 loop -> phase 2)
//   res[w] (16x68 f32): overlay smem + 4352*w  (live: phase 3, per-wave)
__global__ __launch_bounds__(512, 8) void ccam_main(
        const float* __restrict__ x,
        const __hip_bfloat16* __restrict__ MtF,
        const __hip_bfloat16* __restrict__ MbfF,
        const float* __restrict__ aphal,
        const float* __restrict__ gamma,
        float* __restrict__ out) {
    __shared__ __align__(16) char smem[34816];
    float* xb0 = (float*)smem;
    float* xb1 = (float*)(smem + 16640);
    float (*Ep)[16][68] = (float(*)[16][68])smem;

    const int tid  = threadIdx.x;
    const int w    = tid >> 6;        // wave 0..7
    const int lane = tid & 63;
    const int g    = lane >> 4;
    const int r15  = lane & 15;
    const int rowbase = blockIdx.x * 16;
    float* resw = (float*)(smem + (size_t)w * 4352);   // 16 x 68 floats, per wave

    const float alpha = aphal[0];
    const float gam   = gamma[0];

    // ===== Phase 1: energy partials; chunk = 256 contraction cols, 16 chunks =====
    // wave w: stages rows 2w,2w+1 of each chunk; computes slot ks=w (cols 32w..32w+32)
    f32x4 acc0 = {0.f, 0.f, 0.f, 0.f};
    f32x4 acc1 = acc0, acc2 = acc0, acc3 = acc0;
    {
        // prologue: stage chunk 0
#pragma unroll
        for (int i = 0; i < 2; ++i) {
            const float* gp = x + (size_t)(rowbase + 2 * w + i) * 4096 + lane * 4;
            __builtin_amdgcn_global_load_lds(AS1(gp), AS3(xb0 + (2 * w + i) * 260), 16, 0, 0);
        }
        SBAR();
        for (int c = 0; c < 16; ++c) {
            float*       nxt = (c & 1) ? xb0 : xb1;
            const float* cur = (c & 1) ? xb1 : xb0;
            // 1. B-frags for this chunk FIRST (so compiler's B-wait is vmcnt(2), not 0)
            const __hip_bfloat16* bp = MtF + (((size_t)(8 * c + w) * 4) * 64 + lane) * 8;
            frag_ab B0 = load_frag(bp);
            frag_ab B1 = load_frag(bp + 512);
            frag_ab B2 = load_frag(bp + 1024);
            frag_ab B3 = load_frag(bp + 1536);
            SBAR();
            // 2. stage chunk c+1
            if (c < 15) {
#pragma unroll
                for (int i = 0; i < 2; ++i) {
                    const float* gp = x + (size_t)(rowbase + 2 * w + i) * 4096 + (c + 1) * 256 + lane * 4;
                    __builtin_amdgcn_global_load_lds(AS1(gp), AS3(nxt + (2 * w + i) * 260), 16, 0, 0);
                }
                SBAR();
                // 3. counted wait: drain DMA(c) only (newer: 4 B + 2 DMA = 6)
                asm volatile("s_waitcnt vmcnt(6)" ::: "memory");
            } else {
                asm volatile("s_waitcnt vmcnt(4)" ::: "memory");
            }
            SBAR();
            __builtin_amdgcn_s_barrier();    // chunk c fully staged (all waves)
            SBAR();
            // 4. compute chunk c, slot w
            const float* ap = cur + r15 * 260 + 32 * w + 8 * g;
            float4 a0 = *reinterpret_cast<const float4*>(ap);
            float4 a1 = *reinterpret_cast<const float4*>(ap + 4);
            frag_ab a = cvt2(a0, a1);
            acc0 = MFMA16(a, B0, acc0);
            acc1 = MFMA16(a, B1, acc1);
            acc2 = MFMA16(a, B2, acc2);
            acc3 = MFMA16(a, B3, acc3);
            // 5. LDS reads of cur complete -> release buffer for DMA(c+2)
            asm volatile("s_waitcnt lgkmcnt(0)" ::: "memory");
            SBAR();
            __builtin_amdgcn_s_barrier();
            SBAR();
        }
    }
    __syncthreads();   // full drain once; buffers die, Ep region becomes live

    // ===== Phase 1b: partials -> Ep =====
    // D layout: col = r15 (kdim-in-16-tile), row = 4g+reg (channel)
#pragma unroll
    for (int r = 0; r < 4; ++r) {
        Ep[w][4 * g + r][ 0 + r15] = acc0[r];
        Ep[w][4 * g + r][16 + r15] = acc1[r];
        Ep[w][4 * g + r][32 + r15] = acc2[r];
        Ep[w][4 * g + r][48 + r15] = acc3[r];
    }
    __syncthreads();

    // ===== Phase 2: softmax (every wave redundantly; result lands in A-frag layout) =====
    float e[16];
#pragma unroll
    for (int j = 0; j < 16; ++j) e[j] = 0.f;
#pragma unroll
    for (int p = 0; p < 8; ++p) {
        float4 lo  = *reinterpret_cast<const float4*>(&Ep[p][r15][8 * g]);
        float4 lo2 = *reinterpret_cast<const float4*>(&Ep[p][r15][8 * g + 4]);
        float4 hi  = *reinterpret_cast<const float4*>(&Ep[p][r15][32 + 8 * g]);
        float4 hi2 = *reinterpret_cast<const float4*>(&Ep[p][r15][32 + 8 * g + 4]);
        e[0] += lo.x;  e[1] += lo.y;  e[2]  += lo.z;  e[3]  += lo.w;
        e[4] += lo2.x; e[5] += lo2.y; e[6]  += lo2.z; e[7]  += lo2.w;
        e[8] += hi.x;  e[9] += hi.y;  e[10] += hi.z;  e[11] += hi.w;
        e[12] += hi2.x; e[13] += hi2.y; e[14] += hi2.z; e[15] += hi2.w;
    }
    float m = e[0];
#pragma unroll
    for (int j = 1; j < 16; ++j) m = fmaxf(m, e[j]);
    m = fmaxf(m, __shfl_xor(m, 16, 64));
    m = fmaxf(m, __shfl_xor(m, 32, 64));
#pragma unroll
    for (int j = 0; j < 16; ++j) e[j] = alpha * (m - e[j]);   // reuse e as v
    float vm = e[0];
#pragma unroll
    for (int j = 1; j < 16; ++j) vm = fmaxf(vm, e[j]);
    vm = fmaxf(vm, __shfl_xor(vm, 16, 64));
    vm = fmaxf(vm, __shfl_xor(vm, 32, 64));
    float s = 0.f;
#pragma unroll
    for (int j = 0; j < 16; ++j) { e[j] = __expf(e[j] - vm); s += e[j]; }
    s += __shfl_xor(s, 16, 64);
    s += __shfl_xor(s, 32, 64);
    const float sc = gam / s;                 // fold gamma into attention
    frag_ab A0, A1;   // row = r15 (channel), k = 8g+j (A0) / 32+8g+j (A1)
#pragma unroll
    for (int j = 0; j < 8; ++j) {
        A0[j] = (short)f2bf_bits(e[j] * sc);
        A1[j] = (short)f2bf_bits(e[8 + j] * sc);
    }
    __syncthreads();   // Ep dead; res region becomes live

    // ===== Phase 3: out = (gam*att) @ M^T + x ; wave-private, no barriers =====
    // wave w covers n in [512w, 512w+512), 8 grps of 64 cols
    const int nb0 = w * 512;
    // prologue: residual DMA for grp 0 (16 rows x 64 f32, 256 B/instr)
#pragma unroll
    for (int i = 0; i < 16; ++i) {
        const float* gp = x + (size_t)(rowbase + i) * 4096 + nb0 + lane;
        __builtin_amdgcn_global_load_lds(AS1(gp), AS3(resw + i * 68), 4, 0, 0);
    }
    SBAR();
    for (int grp = 0; grp < 8; ++grp) {
        const int nbase = nb0 + grp * 64;
        const int nt0   = 32 * w + 4 * grp;
        // B-frags (issued after res DMA(grp) -> B-waits drain the DMA progressively)
        const __hip_bfloat16* bb = MbfF + ((size_t)nt0 * 2 * 64 + lane) * 8;
        frag_ab b00 = load_frag(bb);
        frag_ab b01 = load_frag(bb + 512);
        frag_ab b10 = load_frag(bb + 1024);
        frag_ab b11 = load_frag(bb + 1536);
        frag_ab b20 = load_frag(bb + 2048);
        frag_ab b21 = load_frag(bb + 2560);
        frag_ab b30 = load_frag(bb + 3072);
        frag_ab b31 = load_frag(bb + 3584);
        f32x4 d0 = {0.f, 0.f, 0.f, 0.f};
        f32x4 d1 = d0, d2 = d0, d3 = d0;
        d0 = MFMA16(A0, b00, d0); d0 = MFMA16(A1, b01, d0);
        d1 = MFMA16(A0, b10, d1); d1 = MFMA16(A1, b11, d1);
        d2 = MFMA16(A0, b20, d2); d2 = MFMA16(A1, b21, d2);
        d3 = MFMA16(A0, b30, d3); d3 = MFMA16(A1, b31, d3);
        // fence: res DMA(grp) landed; keep ds_reads below (untracked dep, rule 18)
        asm volatile("s_waitcnt vmcnt(0)" ::: "memory");
        SBAR();
        // residual reads (per r: 4 scalar LDS reads)
        float rv[16];
#pragma unroll
        for (int r = 0; r < 4; ++r) {
            const float* rr = resw + (4 * g + r) * 68 + r15;
            rv[r * 4 + 0] = rr[ 0];
            rv[r * 4 + 1] = rr[16];
            rv[r * 4 + 2] = rr[32];
            rv[r * 4 + 3] = rr[48];
        }
        // reads retired -> safe to overwrite resw with next grp's DMA
        asm volatile("s_waitcnt lgkmcnt(0)" ::: "memory");
        SBAR();
        if (grp < 7) {
#pragma unroll
            for (int i = 0; i < 16; ++i) {
                const float* gp = x + (size_t)(rowbase + i) * 4096 + nbase + 64 + lane;
                __builtin_amdgcn_global_load_lds(AS1(gp), AS3(resw + i * 68), 4, 0, 0);
            }
            SBAR();
        }
        // epilogue: add residual, store (4 rows x 4 cols per lane, 64B segments/wave)
#pragma unroll
        for (int r = 0; r < 4; ++r) {
            float* op = out + (size_t)(rowbase + 4 * g + r) * 4096 + nbase + r15;
            op[ 0] = d0[r] + rv[r * 4 + 0];
            op[16] = d1[r] + rv[r * 4 + 1];
            op[32] = d2[r] + rv[r * 4 + 2];
            op[48] = d3[r] + rv[r * 4 + 3];
        }
    }
}

extern "C" void kernel_launch(void* const* d_in, const int* in_sizes, int n_in,
                              void* d_out, int out_size, void* d_ws, size_t ws_size,
                              hipStream_t stream) {
    const float* x     = (const float*)d_in[0];
    const float* M     = (const float*)d_in[1];
    const float* aphal = (const float*)d_in[2];
    const float* gamma = (const float*)d_in[3];
    __hip_bfloat16* MtF  = (__hip_bfloat16*)d_ws;                  // 512 KB
    __hip_bfloat16* MbfF = (__hip_bfloat16*)d_ws + 64 * 4096;      // 512 KB

    hipLaunchKernelGGL(prep_frags, dim3(256), dim3(256), 0, stream, M, MtF, MbfF);
    hipLaunchKernelGGL(ccam_main, dim3(1024), dim3(512), 0, stream,
                       x, MtF, MbfF, aphal, gamma, (float*)d_out);
}

// Round 6
// 169.941 us; speedup vs baseline: 1.6311x; 1.6311x over previous
//
#include <hip/hip_runtime.h>
#include <hip/hip_bf16.h>

// CCAM (fp32 in/out): x (16,1024,64,64), martx (4096,64).
// rows = B*C = 16384, N = 4096 spatial, KDIM = 64.
// energy[r][k] = sum_n x[r][n] * M[n][k]           (GEMM1, K=4096)
// att = softmax(alpha * (rowmax(energy) - energy))  (64-wide)
// out[r][n] = gamma * sum_k att[r][k]*M[n][k] + x[r][n]
//
// Round-6: round-5 skeleton, two fixes:
//   - __launch_bounds__(512,4): 16 waves/CU with a 128-VGPR budget (round 5's
//     (512,8) squeezed to 32 VGPRs and serialized everything)
//   - true pipelining: phase 1 depth-2 (3 LDS buffers, B prefetched 1 chunk
//     ahead, steady-state s_waitcnt vmcnt(8)); phase 3 double-buffered
//     residual LDS with vmcnt(16) (DMAs in flight across iterations)

using frag_ab = __attribute__((ext_vector_type(8))) short;   // 8 bf16 = 4 VGPR
using f32x4   = __attribute__((ext_vector_type(4))) float;   // MFMA C/D

#define MFMA16(a, b, c) __builtin_amdgcn_mfma_f32_16x16x32_bf16((a), (b), (c), 0, 0, 0)
#define AS1(p) ((const __attribute__((address_space(1))) void*)(p))
#define AS3(p) ((__attribute__((address_space(3))) void*)(p))
#define SBAR() __builtin_amdgcn_sched_barrier(0)

static __device__ __forceinline__ unsigned short f2bf_bits(float f) {
    __hip_bfloat16 h = __float2bfloat16(f);
    return *reinterpret_cast<const unsigned short*>(&h);
}
static __device__ __forceinline__ frag_ab load_frag(const __hip_bfloat16* p) {
    return *reinterpret_cast<const frag_ab*>(p);
}
static __device__ __forceinline__ frag_ab cvt2(float4 a, float4 b) {
    frag_ab r;
    r[0] = (short)f2bf_bits(a.x); r[1] = (short)f2bf_bits(a.y);
    r[2] = (short)f2bf_bits(a.z); r[3] = (short)f2bf_bits(a.w);
    r[4] = (short)f2bf_bits(b.x); r[5] = (short)f2bf_bits(b.y);
    r[6] = (short)f2bf_bits(b.z); r[7] = (short)f2bf_bits(b.w);
    return r;
}

// -------- kernel 0: build frag-linear B banks (unchanged, validated) --------
// MtF  (512 frags x 1 KB): frag f = slot*4+t, elem (lane,j) = M[32*slot+8g+j][16t+r15]
// MbfF (512 frags x 1 KB): frag f = nt*2+h,   elem (lane,j) = M[16nt+r15][32h+8g+j]
__global__ __launch_bounds__(256) void prep_frags(
        const float* __restrict__ M,
        __hip_bfloat16* __restrict__ MtF, __hip_bfloat16* __restrict__ MbfF) {
    const int w    = threadIdx.x >> 6;
    const int lane = threadIdx.x & 63;
    const int g    = lane >> 4;
    const int r15  = lane & 15;
    const int f    = blockIdx.x * 4 + w;    // 0..1023
    if (f < 512) {
        const int slot = f >> 2, t = f & 3;
        frag_ab fr;
#pragma unroll
        for (int j = 0; j < 8; ++j)
            fr[j] = (short)f2bf_bits(M[(size_t)(32 * slot + 8 * g + j) * 64 + 16 * t + r15]);
        *reinterpret_cast<frag_ab*>(MtF + ((size_t)f * 64 + lane) * 8) = fr;
    } else {
        const int f2 = f - 512;
        const float* src = M + (size_t)(16 * (f2 >> 1) + r15) * 64 + 32 * (f2 & 1) + 8 * g;
        float4 a = *reinterpret_cast<const float4*>(src);
        float4 b = *reinterpret_cast<const float4*>(src + 4);
        *reinterpret_cast<frag_ab*>(MbfF + ((size_t)f2 * 64 + lane) * 8) = cvt2(a, b);
    }
}

// -------- kernel 1: fused CCAM ----------------------------------------------
// LDS (69632 B):
//   phase 1: xbuf[3] at 0 / 16640 / 33280 (16 rows x 260 floats each)
//   phase 2: Ep[8][16][68] overlay at 0
//   phase 3: per-wave res double buffer at w*8704 (2 x 16 x 68 floats)
__global__ __launch_bounds__(512, 4) void ccam_main(
        const float* __restrict__ x,
        const __hip_bfloat16* __restrict__ MtF,
        const __hip_bfloat16* __restrict__ MbfF,
        const float* __restrict__ aphal,
        const float* __restrict__ gamma,
        float* __restrict__ out) {
    __shared__ __align__(16) char smem[69632];
    float* xb[3] = { (float*)smem, (float*)(smem + 16640), (float*)(smem + 33280) };
    float (*Ep)[16][68] = (float(*)[16][68])smem;

    const int tid  = threadIdx.x;
    const int w    = tid >> 6;        // wave 0..7
    const int lane = tid & 63;
    const int g    = lane >> 4;
    const int r15  = lane & 15;
    const int rowbase = blockIdx.x * 16;
    float* res0 = (float*)(smem + (size_t)w * 8704);   // 16 x 68 floats
    float* res1 = res0 + 1088;

    const float alpha = aphal[0];
    const float gam   = gamma[0];

    // ===== Phase 1: energy partials; chunk = 256 contraction cols, 16 chunks =====
    // wave w: stages rows 2w,2w+1 of each chunk; computes col-slot w (32 cols)
    f32x4 acc0 = {0.f, 0.f, 0.f, 0.f};
    f32x4 acc1 = acc0, acc2 = acc0, acc3 = acc0;
    {
        frag_ab Bc0, Bc1, Bc2, Bc3, Bn0, Bn1, Bn2, Bn3;
        // prologue: DMA(0), B(0), DMA(1)   [this exact order sets the counts]
#pragma unroll
        for (int i = 0; i < 2; ++i)
            __builtin_amdgcn_global_load_lds(
                AS1(x + (size_t)(rowbase + 2 * w + i) * 4096 + lane * 4),
                AS3(xb[0] + (2 * w + i) * 260), 16, 0, 0);
        {
            const __hip_bfloat16* bp = MtF + (((size_t)w * 4) * 64 + lane) * 8;
            Bc0 = load_frag(bp);
            Bc1 = load_frag(bp + 512);
            Bc2 = load_frag(bp + 1024);
            Bc3 = load_frag(bp + 1536);
        }
#pragma unroll
        for (int i = 0; i < 2; ++i)
            __builtin_amdgcn_global_load_lds(
                AS1(x + (size_t)(rowbase + 2 * w + i) * 4096 + 256 + lane * 4),
                AS3(xb[1] + (2 * w + i) * 260), 16, 0, 0);
        SBAR();

#pragma unroll
        for (int c = 0; c < 16; ++c) {
            // 1. prefetch B(c+1) into Bn (4 x 1KB contiguous, L2-resident)
            if (c < 15) {
                const __hip_bfloat16* bp = MtF + (((size_t)(8 * (c + 1) + w) * 4) * 64 + lane) * 8;
                Bn0 = load_frag(bp);
                Bn1 = load_frag(bp + 512);
                Bn2 = load_frag(bp + 1024);
                Bn3 = load_frag(bp + 1536);
            }
            // 2. DMA chunk c+2
            if (c < 14) {
#pragma unroll
                for (int i = 0; i < 2; ++i)
                    __builtin_amdgcn_global_load_lds(
                        AS1(x + (size_t)(rowbase + 2 * w + i) * 4096 + (c + 2) * 256 + lane * 4),
                        AS3(xb[(c + 2) % 3] + (2 * w + i) * 260), 16, 0, 0);
            }
            SBAR();
            // 3. wait: DMA(c) + B(c) retired; DMA(c+1), B(c+1), DMA(c+2) in flight
            if (c <= 13)      asm volatile("s_waitcnt vmcnt(8)" ::: "memory");
            else if (c == 14) asm volatile("s_waitcnt vmcnt(6)" ::: "memory");
            else              asm volatile("s_waitcnt vmcnt(0)" ::: "memory");
            SBAR();
            __builtin_amdgcn_s_barrier();     // chunk c staged by all waves
            SBAR();
            // 4. compute chunk c, col-slot w
            {
                const float* ap = xb[c % 3] + r15 * 260 + 32 * w + 8 * g;
                float4 a0 = *reinterpret_cast<const float4*>(ap);
                float4 a1 = *reinterpret_cast<const float4*>(ap + 4);
                frag_ab a = cvt2(a0, a1);
                acc0 = MFMA16(a, Bc0, acc0);
                acc1 = MFMA16(a, Bc1, acc1);
                acc2 = MFMA16(a, Bc2, acc2);
                acc3 = MFMA16(a, Bc3, acc3);
            }
            // 5. release buffer (WAR for DMA(c+3) issued next iteration)
            asm volatile("s_waitcnt lgkmcnt(0)" ::: "memory");
            SBAR();
            __builtin_amdgcn_s_barrier();
            SBAR();
            Bc0 = Bn0; Bc1 = Bn1; Bc2 = Bn2; Bc3 = Bn3;
        }
    }
    __syncthreads();   // xbufs die; Ep region becomes live

    // ===== Phase 1b: partials -> Ep =====
    // D layout: col = r15 (kdim-in-16-tile), row = 4g+reg (channel)
#pragma unroll
    for (int r = 0; r < 4; ++r) {
        Ep[w][4 * g + r][ 0 + r15] = acc0[r];
        Ep[w][4 * g + r][16 + r15] = acc1[r];
        Ep[w][4 * g + r][32 + r15] = acc2[r];
        Ep[w][4 * g + r][48 + r15] = acc3[r];
    }
    __syncthreads();

    // ===== Phase 2: softmax (every wave redundantly; lands in A-frag layout) =====
    float e[16];
#pragma unroll
    for (int j = 0; j < 16; ++j) e[j] = 0.f;
#pragma unroll
    for (int p = 0; p < 8; ++p) {
        float4 lo  = *reinterpret_cast<const float4*>(&Ep[p][r15][8 * g]);
        float4 lo2 = *reinterpret_cast<const float4*>(&Ep[p][r15][8 * g + 4]);
        float4 hi  = *reinterpret_cast<const float4*>(&Ep[p][r15][32 + 8 * g]);
        float4 hi2 = *reinterpret_cast<const float4*>(&Ep[p][r15][32 + 8 * g + 4]);
        e[0] += lo.x;  e[1] += lo.y;  e[2]  += lo.z;  e[3]  += lo.w;
        e[4] += lo2.x; e[5] += lo2.y; e[6]  += lo2.z; e[7]  += lo2.w;
        e[8] += hi.x;  e[9] += hi.y;  e[10] += hi.z;  e[11] += hi.w;
        e[12] += hi2.x; e[13] += hi2.y; e[14] += hi2.z; e[15] += hi2.w;
    }
    float m = e[0];
#pragma unroll
    for (int j = 1; j < 16; ++j) m = fmaxf(m, e[j]);
    m = fmaxf(m, __shfl_xor(m, 16, 64));
    m = fmaxf(m, __shfl_xor(m, 32, 64));
#pragma unroll
    for (int j = 0; j < 16; ++j) e[j] = alpha * (m - e[j]);
    float vm = e[0];
#pragma unroll
    for (int j = 1; j < 16; ++j) vm = fmaxf(vm, e[j]);
    vm = fmaxf(vm, __shfl_xor(vm, 16, 64));
    vm = fmaxf(vm, __shfl_xor(vm, 32, 64));
    float s = 0.f;
#pragma unroll
    for (int j = 0; j < 16; ++j) { e[j] = __expf(e[j] - vm); s += e[j]; }
    s += __shfl_xor(s, 16, 64);
    s += __shfl_xor(s, 32, 64);
    const float sc = gam / s;                 // fold gamma into attention
    frag_ab A0, A1;   // row = r15 (channel), k = 8g+j (A0) / 32+8g+j (A1)
#pragma unroll
    for (int j = 0; j < 8; ++j) {
        A0[j] = (short)f2bf_bits(e[j] * sc);
        A1[j] = (short)f2bf_bits(e[8 + j] * sc);
    }
    __syncthreads();   // Ep dead; res region becomes live

    // ===== Phase 3: out = (gam*att) @ M^T + x ; wave-private, no barriers =====
    // wave w covers n in [512w, 512w+512): 8 grps of 64 cols; res double-buffered
    const int nb0 = w * 512;
    // prologue: residual DMA grp 0 -> res0 (16 rows x 256 B)
#pragma unroll
    for (int i = 0; i < 16; ++i)
        __builtin_amdgcn_global_load_lds(
            AS1(x + (size_t)(rowbase + i) * 4096 + nb0 + lane),
            AS3(res0 + i * 68), 4, 0, 0);
    SBAR();
#pragma unroll
    for (int grp = 0; grp < 8; ++grp) {
        const int nbase = nb0 + grp * 64;
        const int nt0   = 32 * w + 4 * grp;
        float* rcur = (grp & 1) ? res1 : res0;
        float* rnxt = (grp & 1) ? res0 : res1;
        // 1. B(grp) first (so the B-wait leaves DMA(grp+1) in flight)
        const __hip_bfloat16* bb = MbfF + ((size_t)nt0 * 2 * 64 + lane) * 8;
        frag_ab b00 = load_frag(bb);
        frag_ab b01 = load_frag(bb + 512);
        frag_ab b10 = load_frag(bb + 1024);
        frag_ab b11 = load_frag(bb + 1536);
        frag_ab b20 = load_frag(bb + 2048);
        frag_ab b21 = load_frag(bb + 2560);
        frag_ab b30 = load_frag(bb + 3072);
        frag_ab b31 = load_frag(bb + 3584);
        SBAR();
        // 2. DMA grp+1 residual into the other buffer
        if (grp < 7) {
#pragma unroll
            for (int i = 0; i < 16; ++i)
                __builtin_amdgcn_global_load_lds(
                    AS1(x + (size_t)(rowbase + i) * 4096 + nbase + 64 + lane),
                    AS3(rnxt + i * 68), 4, 0, 0);
        }
        SBAR();
        // 3. wait: DMA(grp) + B(grp) retired; DMA(grp+1) stays in flight
        if (grp < 7) asm volatile("s_waitcnt vmcnt(16)" ::: "memory");
        else         asm volatile("s_waitcnt vmcnt(0)" ::: "memory");
        SBAR();
        // 4. MFMA (B already waited) + residual reads from rcur
        f32x4 d0 = {0.f, 0.f, 0.f, 0.f};
        f32x4 d1 = d0, d2 = d0, d3 = d0;
        d0 = MFMA16(A0, b00, d0); d0 = MFMA16(A1, b01, d0);
        d1 = MFMA16(A0, b10, d1); d1 = MFMA16(A1, b11, d1);
        d2 = MFMA16(A0, b20, d2); d2 = MFMA16(A1, b21, d2);
        d3 = MFMA16(A0, b30, d3); d3 = MFMA16(A1, b31, d3);
        float rv[16];
#pragma unroll
        for (int r = 0; r < 4; ++r) {
            const float* rr = rcur + (4 * g + r) * 68 + r15;
            rv[r * 4 + 0] = rr[ 0];
            rv[r * 4 + 1] = rr[16];
            rv[r * 4 + 2] = rr[32];
            rv[r * 4 + 3] = rr[48];
        }
        asm volatile("s_waitcnt lgkmcnt(0)" ::: "memory");  // rcur reads done (WAR)
        SBAR();
        // 5. store out
#pragma unroll
        for (int r = 0; r < 4; ++r) {
            float* op = out + (size_t)(rowbase + 4 * g + r) * 4096 + nbase + r15;
            op[ 0] = d0[r] + rv[r * 4 + 0];
            op[16] = d1[r] + rv[r * 4 + 1];
            op[32] = d2[r] + rv[r * 4 + 2];
            op[48] = d3[r] + rv[r * 4 + 3];
        }
    }
}

extern "C" void kernel_launch(void* const* d_in, const int* in_sizes, int n_in,
                              void* d_out, int out_size, void* d_ws, size_t ws_size,
                              hipStream_t stream) {
    const float* x     = (const float*)d_in[0];
    const float* M     = (const float*)d_in[1];
    const float* aphal = (const float*)d_in[2];
    const float* gamma = (const float*)d_in[3];
    __hip_bfloat16* MtF  = (__hip_bfloat16*)d_ws;                  // 512 KB
    __hip_bfloat16* MbfF = (__hip_bfloat16*)d_ws + 64 * 4096;      // 512 KB

    hipLaunchKernelGGL(prep_frags, dim3(256), dim3(256), 0, stream, M, MtF, MbfF);
    hipLaunchKernelGGL(ccam_main, dim3(1024), dim3(512), 0, stream,
                       x, MtF, MbfF, aphal, gamma, (float*)d_out);
}